// Round 5
// baseline (177.455 us; speedup 1.0000x reference)
//
#include <hip/hip_runtime.h>
#include <math.h>

#define Bq 4
#define Hh 8
#define Lh 2048
#define Dh 64
#define BH (Bq*Hh)

// ---------------- Kernel AC: fused kA (sampled-score partials) + kC (V col sums) ----
// blocks [0,2048): kA half-sample partials. Each block: (bh, qtile of 64, half).
//   Writes M2[gq*2+half] = (max, sum) over its ~20 samples.
// blocks [2048,2304): kC V column partial sums (independent of kA).
__global__ __launch_bounds__(256) void kAC(const float* __restrict__ Q,
                                           const float* __restrict__ K,
                                           const float* __restrict__ V,
                                           const int* __restrict__ idxs,
                                           float2* __restrict__ M2,
                                           float* __restrict__ vpart, int u) {
    int bi = blockIdx.x;
    int tid = threadIdx.x;
    if (bi < 2048) {
        // ---- kA path ----
        int xcd = bi & 7, slot = bi >> 3;      // slot 0..255
        int bh  = xcd * 4 + (slot >> 6);       // 0..31
        int qt  = (slot >> 1) & 31;            // 0..31
        int half = slot & 1;
        int wave = tid >> 6, lane = tid & 63;
        int g = lane >> 2, c = lane & 3;       // 16 groups x 4 lanes
        int q = qt * 64 + wave * 16 + g;
        long gq = (long)bh * Lh + q;

        const float* qrow = Q + gq * Dh;
        float4 qf[4];
#pragma unroll
        for (int jj = 0; jj < 4; ++jj)
            qf[jj] = *(const float4*)(qrow + jj * 16 + c * 4);

        int cnt1 = u >> 1;                     // half1 count
        int c0 = (half == 0) ? (u - cnt1) : cnt1;
        const int* irow = idxs + (long)q * u + (half ? (u - cnt1) : 0);
        const float* kbase = K + (long)bh * Lh * Dh;

        float mx = -INFINITY, sm = 0.f;
        int s = 0;
        for (; s + 4 <= c0; s += 4) {
            int i0 = irow[s], i1 = irow[s+1], i2 = irow[s+2], i3 = irow[s+3];
            const float* kp0 = kbase + (long)i0 * Dh + c * 4;
            const float* kp1 = kbase + (long)i1 * Dh + c * 4;
            const float* kp2 = kbase + (long)i2 * Dh + c * 4;
            const float* kp3 = kbase + (long)i3 * Dh + c * 4;
            float4 kf[4][4];
#pragma unroll
            for (int jj = 0; jj < 4; ++jj) {
                kf[0][jj] = *(const float4*)(kp0 + jj * 16);
                kf[1][jj] = *(const float4*)(kp1 + jj * 16);
                kf[2][jj] = *(const float4*)(kp2 + jj * 16);
                kf[3][jj] = *(const float4*)(kp3 + jj * 16);
            }
            float a[4];
#pragma unroll
            for (int r = 0; r < 4; ++r) {
                float ac = 0.f;
#pragma unroll
                for (int jj = 0; jj < 4; ++jj)
                    ac += qf[jj].x*kf[r][jj].x + qf[jj].y*kf[r][jj].y
                        + qf[jj].z*kf[r][jj].z + qf[jj].w*kf[r][jj].w;
                a[r] = ac;
            }
#pragma unroll
            for (int r = 0; r < 4; ++r) {
                a[r] += __shfl_xor(a[r], 1);
                a[r] += __shfl_xor(a[r], 2);
                mx = fmaxf(mx, a[r]); sm += a[r];
            }
        }
        for (; s < c0; ++s) {
            int ki = irow[s];
            const float* krow = kbase + (long)ki * Dh + c * 4;
            float acc = 0.f;
#pragma unroll
            for (int jj = 0; jj < 4; ++jj) {
                float4 kf = *(const float4*)(krow + jj * 16);
                acc += qf[jj].x*kf.x + qf[jj].y*kf.y + qf[jj].z*kf.z + qf[jj].w*kf.w;
            }
            acc += __shfl_xor(acc, 1);
            acc += __shfl_xor(acc, 2);
            mx = fmaxf(mx, acc); sm += acc;
        }
        if (c == 0) M2[gq * 2 + half] = make_float2(mx, sm);
    } else {
        // ---- kC path ----
        int b2 = bi - 2048;
        int xcd = b2 & 7, slot = b2 >> 3;
        int bh = xcd * 4 + (slot >> 3);
        int chunk = slot & 7;
        int d = tid & 63, r0 = tid >> 6;
        const float* vb = V + ((long)bh * Lh + chunk * 256) * Dh;
        float s = 0.f;
        for (int i = 0; i < 64; ++i) s += vb[(r0 + 4 * i) * Dh + d];
        __shared__ float part[4][64];
        part[r0][d] = s;
        __syncthreads();
        if (tid < 64) {
            float t = part[0][tid] + part[1][tid] + part[2][tid] + part[3][tid];
            vpart[(bh * 8 + chunk) * 64 + tid] = t;
        }
    }
}

// ---------------- Kernel BE: fused kE (mean fill) + kB (radix top-U) ----------------
// blocks [0,4096): kE fill ctx with V-mean. blocks [4096,4128): kB top-U per bh.
__global__ __launch_bounds__(256) void kBE(const float2* __restrict__ M2,
                                           const float* __restrict__ vpart,
                                           int* __restrict__ topk,
                                           float* __restrict__ ctx, int U) {
    int bi = blockIdx.x;
    int tid = threadIdx.x;
    if (bi < 4096) {
        // ---- kE path ----
        long base = (long)bi * 1024;
        int bh = (int)(base >> 17);
        __shared__ float vm[64];
        if (tid < 64) {
            float s = 0.f;
#pragma unroll
            for (int c2 = 0; c2 < 8; ++c2) s += vpart[(bh * 8 + c2) * 64 + tid];
            vm[tid] = s * (1.0f / (float)Lh);
        }
        __syncthreads();
        float4 val = *(const float4*)(vm + ((tid * 4) & 63));
        *(float4*)(ctx + base + tid * 4) = val;
        return;
    }
    // ---- kB path ----
    int bh = bi - 4096;
    unsigned key[8];
#pragma unroll
    for (int j = 0; j < 8; ++j) {
        long q = (long)bh * Lh + tid + 256 * j;
        float4 mm = *(const float4*)(&M2[q * 2]);   // {m0,s0,m1,s1}
        float Mv = fmaxf(mm.x, mm.z) - (mm.y + mm.w) * (1.0f / (float)Lh);
        unsigned ub = __float_as_uint(Mv);
        key[j] = ub ^ ((ub >> 31) ? 0xFFFFFFFFu : 0x80000000u);
    }
    __shared__ unsigned hist[256];
    __shared__ unsigned prefix_s;
    __shared__ int need_s;
    if (tid == 0) { prefix_s = 0u; need_s = U; }

    for (int level = 3; level >= 0; --level) {
        int shift = level * 8;
        hist[tid] = 0u;
        __syncthreads();
        unsigned prefix = prefix_s;
        int need = need_s;
        unsigned pmask = (level == 3) ? 0u : (0xFFFFFFFFu << (shift + 8));
#pragma unroll
        for (int j = 0; j < 8; ++j)
            if ((key[j] & pmask) == prefix)
                atomicAdd(&hist[(key[j] >> shift) & 0xFF], 1u);
        __syncthreads();
        if (tid < 64) {
            int lane = tid;
            unsigned h0 = hist[lane*4+0], h1 = hist[lane*4+1],
                     h2 = hist[lane*4+2], h3 = hist[lane*4+3];
            unsigned lt = h0 + h1 + h2 + h3;
            unsigned ssum = lt;
#pragma unroll
            for (int off = 1; off < 64; off <<= 1) {
                unsigned t = __shfl_down(ssum, off);
                if (lane + off < 64) ssum += t;
            }
            unsigned sx  = ssum - lt;
            unsigned suf3 = sx  + h3;
            unsigned suf2 = suf3 + h2;
            unsigned suf1 = suf2 + h1;
            unsigned suf0 = suf1 + h0;
            int localb = -1; unsigned nxt = 0u;
            if      ((int)suf3 >= need) { localb = lane*4+3; nxt = sx;   }
            else if ((int)suf2 >= need) { localb = lane*4+2; nxt = suf3; }
            else if ((int)suf1 >= need) { localb = lane*4+1; nxt = suf2; }
            else if ((int)suf0 >= need) { localb = lane*4+0; nxt = suf1; }
            unsigned long long ball = __ballot(localb >= 0);
            int hilane = 63 - __clzll(ball);
            if (lane == hilane) {
                prefix_s = prefix | ((unsigned)localb << shift);
                need_s = need - (int)nxt;
            }
        }
        __syncthreads();
    }
    unsigned T = prefix_s;
    int r = need_s;
    __shared__ int cgt, ceq;
    if (tid == 0) { cgt = 0; ceq = 0; }
    __syncthreads();
    int* out = topk + bh * U;
#pragma unroll
    for (int j = 0; j < 8; ++j) {
        if (key[j] > T) { int p = atomicAdd(&cgt, 1); out[p] = tid + 256 * j; }
        else if (key[j] == T) { int e = atomicAdd(&ceq, 1); if (e < r) out[U - r + e] = tid + 256 * j; }
    }
}

// ---------------- Kernel D: split-K partial attention (v4) ----------------
// Block = (bh, u-chunk of 8 q, key-chunk of 256 k); 4 tiles of 64 keys.
// NO K/V LDS staging: score phase reads K rows direct from global (lane=key;
// 16KB tile is L1-resident across the 4 waves); PV reads V direct (coalesced).
// Ps/alph ping-pong -> exactly ONE barrier per tile.
#define TK 64
__global__ __launch_bounds__(256) void kD_part(const float* __restrict__ Q,
                                               const float* __restrict__ K,
                                               const float* __restrict__ V,
                                               const int* __restrict__ topk,
                                               float* __restrict__ pm,
                                               float* __restrict__ pl,
                                               float* __restrict__ pacc,
                                               int U, int nch) {
    int bi = blockIdx.x;
    int xcd = bi & 7, slot = bi >> 3;
    int per = nch * 8;
    int bh = xcd * 4 + slot / per;
    int rest = slot % per;
    int uc = rest >> 3, kc = rest & 7;

    int tid = threadIdx.x;
    int wv = tid >> 6, lane = tid & 63;

    __shared__ float Qs[8 * 64];
    __shared__ float Ps[2][8 * 68];
    __shared__ float alph[2][8];
    __shared__ float mst[8], lst[8];
    __shared__ int   qidxs[8];
    __shared__ float accbuf[4 * 512];

    if (tid < 8) {
        int gu = uc * 8 + tid;
        qidxs[tid] = (gu < U) ? topk[bh * U + gu] : 0;
    }
    __syncthreads();
#pragma unroll
    for (int step = 0; step < 2; ++step) {
        int uu = step * 4 + wv;
        int row = qidxs[uu];
        Qs[uu * 64 + lane] = Q[((long)bh * Lh + row) * Dh + lane] * 0.125f;
    }
    __syncthreads();                           // Qs visible to all waves

    int kq = lane, ug = wv;
    float mrun0 = -INFINITY, mrun1 = -INFINITY;
    float lrun0 = 0.f, lrun1 = 0.f;
    float accv[8] = {0.f,0.f,0.f,0.f,0.f,0.f,0.f,0.f};

    const long kvbase = (long)bh * Lh * Dh;
    const float* Kg = K + kvbase;
    const float* Vg = V + kvbase;
    int kbase0 = kc * 256;

    for (int t = 0; t < 4; ++t) {
        int t0 = kbase0 + t * TK;
        int pp = t & 1;
        // ---- scores: K row (t0+kq) direct from global; Qs broadcast from LDS ----
        const float4* kr = (const float4*)(Kg + (long)(t0 + kq) * Dh);
        float s0 = 0.f, s1 = 0.f;
#pragma unroll
        for (int j16 = 0; j16 < 16; ++j16) {
            float4 kf = kr[j16];
            float4 qa = *(const float4*)(&Qs[(2 * ug + 0) * 64 + j16 * 4]);
            float4 qb = *(const float4*)(&Qs[(2 * ug + 1) * 64 + j16 * 4]);
            s0 += kf.x * qa.x + kf.y * qa.y + kf.z * qa.z + kf.w * qa.w;
            s1 += kf.x * qb.x + kf.y * qb.y + kf.z * qb.z + kf.w * qb.w;
        }
        float m0 = s0, m1 = s1;
#pragma unroll
        for (int off = 1; off < 64; off <<= 1) {
            m0 = fmaxf(m0, __shfl_xor(m0, off));
            m1 = fmaxf(m1, __shfl_xor(m1, off));
        }
        float mn0 = fmaxf(mrun0, m0), mn1 = fmaxf(mrun1, m1);
        float a0 = __expf(mrun0 - mn0), a1 = __expf(mrun1 - mn1);
        float p0 = __expf(s0 - mn0),  p1 = __expf(s1 - mn1);
        float ls0 = p0, ls1 = p1;
#pragma unroll
        for (int off = 1; off < 64; off <<= 1) {
            ls0 += __shfl_xor(ls0, off);
            ls1 += __shfl_xor(ls1, off);
        }
        lrun0 = a0 * lrun0 + ls0;  lrun1 = a1 * lrun1 + ls1;
        mrun0 = mn0;               mrun1 = mn1;
        Ps[pp][(2 * ug + 0) * 68 + kq] = p0;
        Ps[pp][(2 * ug + 1) * 68 + kq] = p1;
        if (lane == 0) { alph[pp][2 * ug] = a0; alph[pp][2 * ug + 1] = a1; }
        __syncthreads();                       // Ps/alph[pp] visible (1 barrier/tile)

        // ---- PV: lane=d, wave=key-quarter; V direct global, P broadcast b128 ----
        float vk[16];
        int vrow0 = t0 + wv * 16;
#pragma unroll
        for (int k = 0; k < 16; ++k)
            vk[k] = Vg[(long)(vrow0 + k) * Dh + lane];
#pragma unroll
        for (int u2 = 0; u2 < 8; ++u2) {
            const float* pb = &Ps[pp][u2 * 68 + wv * 16];
            float4 pA = *(const float4*)(pb + 0);
            float4 pB = *(const float4*)(pb + 4);
            float4 pC = *(const float4*)(pb + 8);
            float4 pD = *(const float4*)(pb + 12);
            float av = alph[pp][u2];
            float ac = accv[u2] * av;
            ac += pA.x*vk[0]  + pA.y*vk[1]  + pA.z*vk[2]  + pA.w*vk[3];
            ac += pB.x*vk[4]  + pB.y*vk[5]  + pB.z*vk[6]  + pB.w*vk[7];
            ac += pC.x*vk[8]  + pC.y*vk[9]  + pC.z*vk[10] + pC.w*vk[11];
            ac += pD.x*vk[12] + pD.y*vk[13] + pD.z*vk[14] + pD.w*vk[15];
            accv[u2] = ac;
        }
        // no trailing barrier: next tile writes Ps[1-pp] (ping-pong)
    }

    if (lane == 0) {
        mst[2 * ug] = mrun0;     lst[2 * ug] = lrun0;
        mst[2 * ug + 1] = mrun1; lst[2 * ug + 1] = lrun1;
    }
#pragma unroll
    for (int u2 = 0; u2 < 8; ++u2)
        accbuf[wv * 512 + u2 * 64 + lane] = accv[u2];   // own region, no hazard
    __syncthreads();

    int pbase = (bh * nch + uc) * 8;
    {
        int d = tid & 63, ua = tid >> 6;
#pragma unroll
        for (int h = 0; h < 2; ++h) {
            int u2 = ua + 4 * h;
            float o = accbuf[0 * 512 + u2 * 64 + d] + accbuf[1 * 512 + u2 * 64 + d]
                    + accbuf[2 * 512 + u2 * 64 + d] + accbuf[3 * 512 + u2 * 64 + d];
            pacc[((long)(pbase + u2) * 8 + kc) * 64 + d] = o;
        }
    }
    if (tid < 8) {
        int qp = (pbase + tid) * 8 + kc;
        pm[qp] = mst[tid];
        pl[qp] = lst[tid];
    }
}

// ---------------- Kernel F: combine split-K partials, scatter to ctx ----------------
__global__ __launch_bounds__(256) void kF_comb(const float* __restrict__ pm,
                                               const float* __restrict__ pl,
                                               const float* __restrict__ pacc,
                                               const int* __restrict__ topk,
                                               float* __restrict__ ctx,
                                               int U, int nch) {
    int bi = blockIdx.x;
    int bh = bi / nch, uc = bi % nch;
    int tid = threadIdx.x;
    int u = tid >> 5, t = tid & 31;
    int gu = uc * 8 + u;
    if (gu >= U) return;
    int qbase = (bh * nch + uc) * 8 + u;
    float m[8], l[8];
#pragma unroll
    for (int kc = 0; kc < 8; ++kc) { m[kc] = pm[qbase * 8 + kc]; l[kc] = pl[qbase * 8 + kc]; }
    float gm = m[0];
#pragma unroll
    for (int kc = 1; kc < 8; ++kc) gm = fmaxf(gm, m[kc]);
    float w[8]; float gl = 0.f;
#pragma unroll
    for (int kc = 0; kc < 8; ++kc) { w[kc] = __expf(m[kc] - gm); gl += l[kc] * w[kc]; }
    float inv = 1.0f / gl;
    float o0 = 0.f, o1 = 0.f;
#pragma unroll
    for (int kc = 0; kc < 8; ++kc) {
        const float* a = pacc + ((long)qbase * 8 + kc) * 64;
        o0 += a[t] * w[kc];
        o1 += a[t + 32] * w[kc];
    }
    int row = topk[bh * U + gu];
    float* crow = ctx + ((long)bh * Lh + row) * Dh;
    crow[t]      = o0 * inv;
    crow[t + 32] = o1 * inv;
}

extern "C" void kernel_launch(void* const* d_in, const int* in_sizes, int n_in,
                              void* d_out, int out_size, void* d_ws, size_t ws_size,
                              hipStream_t stream) {
    const float* Q    = (const float*)d_in[0];
    const float* K    = (const float*)d_in[1];
    const float* V    = (const float*)d_in[2];
    const int*   idxs = (const int*)d_in[3];
    float* ctx = (float*)d_out;

    int u = in_sizes[3] / Lh;    // 40
    int U = u;
    int nch = (U + 7) / 8;       // 5

    // workspace layout (floats)
    float*  wsf   = (float*)d_ws;
    float2* M2    = (float2*)wsf;                    // 131072 float2 = 262144 f
    int*    topk  = (int*)(wsf + 262144);            // 2048 ints
    float*  vpart = wsf + 262144 + 2048;             // 16384 f
    float*  pm    = wsf + 280576;                    // 32*nch*8*8
    float*  pl    = pm + 32 * nch * 8 * 8;
    float*  pacc  = pl + 32 * nch * 8 * 8;

    kAC    <<<2304,         256, 0, stream>>>(Q, K, V, idxs, M2, vpart, u);
    kBE    <<<4128,         256, 0, stream>>>(M2, vpart, topk, ctx, U);
    kD_part<<<BH * nch * 8, 256, 0, stream>>>(Q, K, V, topk, pm, pl, pacc, U, nch);
    kF_comb<<<BH * nch,     256, 0, stream>>>(pm, pl, pacc, topk, ctx, U, nch);
}

// Round 6
// 153.441 us; speedup vs baseline: 1.1565x; 1.1565x over previous
//
#include <hip/hip_runtime.h>
#include <math.h>

#define Bq 4
#define Hh 8
#define Lh 2048
#define Dh 64
#define BH (Bq*Hh)

// ---------------- Kernel AC: fused kA (sampled-score partials) + kC (V col sums) ----
// blocks [0,2048): kA half-sample partials. Each block: (bh, qtile of 64, half).
//   Writes M2[gq*2+half] = (max, sum) over its ~20 samples.
// blocks [2048,2304): kC V column partial sums (independent of kA).
__global__ __launch_bounds__(256) void kAC(const float* __restrict__ Q,
                                           const float* __restrict__ K,
                                           const float* __restrict__ V,
                                           const int* __restrict__ idxs,
                                           float2* __restrict__ M2,
                                           float* __restrict__ vpart, int u) {
    int bi = blockIdx.x;
    int tid = threadIdx.x;
    if (bi < 2048) {
        // ---- kA path ----
        int xcd = bi & 7, slot = bi >> 3;      // slot 0..255
        int bh  = xcd * 4 + (slot >> 6);       // 0..31
        int qt  = (slot >> 1) & 31;            // 0..31
        int half = slot & 1;
        int wave = tid >> 6, lane = tid & 63;
        int g = lane >> 2, c = lane & 3;       // 16 groups x 4 lanes
        int q = qt * 64 + wave * 16 + g;
        long gq = (long)bh * Lh + q;

        const float* qrow = Q + gq * Dh;
        float4 qf[4];
#pragma unroll
        for (int jj = 0; jj < 4; ++jj)
            qf[jj] = *(const float4*)(qrow + jj * 16 + c * 4);

        int cnt1 = u >> 1;                     // half1 count
        int c0 = (half == 0) ? (u - cnt1) : cnt1;
        const int* irow = idxs + (long)q * u + (half ? (u - cnt1) : 0);
        const float* kbase = K + (long)bh * Lh * Dh;

        float mx = -INFINITY, sm = 0.f;
        int s = 0;
        for (; s + 4 <= c0; s += 4) {
            int i0 = irow[s], i1 = irow[s+1], i2 = irow[s+2], i3 = irow[s+3];
            const float* kp0 = kbase + (long)i0 * Dh + c * 4;
            const float* kp1 = kbase + (long)i1 * Dh + c * 4;
            const float* kp2 = kbase + (long)i2 * Dh + c * 4;
            const float* kp3 = kbase + (long)i3 * Dh + c * 4;
            float4 kf[4][4];
#pragma unroll
            for (int jj = 0; jj < 4; ++jj) {
                kf[0][jj] = *(const float4*)(kp0 + jj * 16);
                kf[1][jj] = *(const float4*)(kp1 + jj * 16);
                kf[2][jj] = *(const float4*)(kp2 + jj * 16);
                kf[3][jj] = *(const float4*)(kp3 + jj * 16);
            }
            float a[4];
#pragma unroll
            for (int r = 0; r < 4; ++r) {
                float ac = 0.f;
#pragma unroll
                for (int jj = 0; jj < 4; ++jj)
                    ac += qf[jj].x*kf[r][jj].x + qf[jj].y*kf[r][jj].y
                        + qf[jj].z*kf[r][jj].z + qf[jj].w*kf[r][jj].w;
                a[r] = ac;
            }
#pragma unroll
            for (int r = 0; r < 4; ++r) {
                a[r] += __shfl_xor(a[r], 1);
                a[r] += __shfl_xor(a[r], 2);
                mx = fmaxf(mx, a[r]); sm += a[r];
            }
        }
        for (; s < c0; ++s) {
            int ki = irow[s];
            const float* krow = kbase + (long)ki * Dh + c * 4;
            float acc = 0.f;
#pragma unroll
            for (int jj = 0; jj < 4; ++jj) {
                float4 kf = *(const float4*)(krow + jj * 16);
                acc += qf[jj].x*kf.x + qf[jj].y*kf.y + qf[jj].z*kf.z + qf[jj].w*kf.w;
            }
            acc += __shfl_xor(acc, 1);
            acc += __shfl_xor(acc, 2);
            mx = fmaxf(mx, acc); sm += acc;
        }
        if (c == 0) M2[gq * 2 + half] = make_float2(mx, sm);
    } else {
        // ---- kC path ----
        int b2 = bi - 2048;
        int xcd = b2 & 7, slot = b2 >> 3;
        int bh = xcd * 4 + (slot >> 3);
        int chunk = slot & 7;
        int d = tid & 63, r0 = tid >> 6;
        const float* vb = V + ((long)bh * Lh + chunk * 256) * Dh;
        float s = 0.f;
        for (int i = 0; i < 64; ++i) s += vb[(r0 + 4 * i) * Dh + d];
        __shared__ float part[4][64];
        part[r0][d] = s;
        __syncthreads();
        if (tid < 64) {
            float t = part[0][tid] + part[1][tid] + part[2][tid] + part[3][tid];
            vpart[(bh * 8 + chunk) * 64 + tid] = t;
        }
    }
}

// ---------------- Kernel BE: fused kE (mean fill) + kB (radix top-U) ----------------
// blocks [0,4096): kE fill ctx with V-mean. blocks [4096,4128): kB top-U per bh.
__global__ __launch_bounds__(256) void kBE(const float2* __restrict__ M2,
                                           const float* __restrict__ vpart,
                                           int* __restrict__ topk,
                                           float* __restrict__ ctx, int U) {
    int bi = blockIdx.x;
    int tid = threadIdx.x;
    if (bi < 4096) {
        // ---- kE path ----
        long base = (long)bi * 1024;
        int bh = (int)(base >> 17);
        __shared__ float vm[64];
        if (tid < 64) {
            float s = 0.f;
#pragma unroll
            for (int c2 = 0; c2 < 8; ++c2) s += vpart[(bh * 8 + c2) * 64 + tid];
            vm[tid] = s * (1.0f / (float)Lh);
        }
        __syncthreads();
        float4 val = *(const float4*)(vm + ((tid * 4) & 63));
        *(float4*)(ctx + base + tid * 4) = val;
        return;
    }
    // ---- kB path ----
    int bh = bi - 4096;
    unsigned key[8];
#pragma unroll
    for (int j = 0; j < 8; ++j) {
        long q = (long)bh * Lh + tid + 256 * j;
        float4 mm = *(const float4*)(&M2[q * 2]);   // {m0,s0,m1,s1}
        float Mv = fmaxf(mm.x, mm.z) - (mm.y + mm.w) * (1.0f / (float)Lh);
        unsigned ub = __float_as_uint(Mv);
        key[j] = ub ^ ((ub >> 31) ? 0xFFFFFFFFu : 0x80000000u);
    }
    __shared__ unsigned hist[256];
    __shared__ unsigned prefix_s;
    __shared__ int need_s;
    if (tid == 0) { prefix_s = 0u; need_s = U; }

    for (int level = 3; level >= 0; --level) {
        int shift = level * 8;
        hist[tid] = 0u;
        __syncthreads();
        unsigned prefix = prefix_s;
        int need = need_s;
        unsigned pmask = (level == 3) ? 0u : (0xFFFFFFFFu << (shift + 8));
#pragma unroll
        for (int j = 0; j < 8; ++j)
            if ((key[j] & pmask) == prefix)
                atomicAdd(&hist[(key[j] >> shift) & 0xFF], 1u);
        __syncthreads();
        if (tid < 64) {
            int lane = tid;
            unsigned h0 = hist[lane*4+0], h1 = hist[lane*4+1],
                     h2 = hist[lane*4+2], h3 = hist[lane*4+3];
            unsigned lt = h0 + h1 + h2 + h3;
            unsigned ssum = lt;
#pragma unroll
            for (int off = 1; off < 64; off <<= 1) {
                unsigned t = __shfl_down(ssum, off);
                if (lane + off < 64) ssum += t;
            }
            unsigned sx  = ssum - lt;
            unsigned suf3 = sx  + h3;
            unsigned suf2 = suf3 + h2;
            unsigned suf1 = suf2 + h1;
            unsigned suf0 = suf1 + h0;
            int localb = -1; unsigned nxt = 0u;
            if      ((int)suf3 >= need) { localb = lane*4+3; nxt = sx;   }
            else if ((int)suf2 >= need) { localb = lane*4+2; nxt = suf3; }
            else if ((int)suf1 >= need) { localb = lane*4+1; nxt = suf2; }
            else if ((int)suf0 >= need) { localb = lane*4+0; nxt = suf1; }
            unsigned long long ball = __ballot(localb >= 0);
            int hilane = 63 - __clzll(ball);
            if (lane == hilane) {
                prefix_s = prefix | ((unsigned)localb << shift);
                need_s = need - (int)nxt;
            }
        }
        __syncthreads();
    }
    unsigned T = prefix_s;
    int r = need_s;
    __shared__ int cgt, ceq;
    if (tid == 0) { cgt = 0; ceq = 0; }
    __syncthreads();
    int* out = topk + bh * U;
#pragma unroll
    for (int j = 0; j < 8; ++j) {
        if (key[j] > T) { int p = atomicAdd(&cgt, 1); out[p] = tid + 256 * j; }
        else if (key[j] == T) { int e = atomicAdd(&ceq, 1); if (e < r) out[U - r + e] = tid + 256 * j; }
    }
}

// ---------------- Kernel D: split-K partial attention (v3 revert) ----------------
// Block = (bh, u-chunk of 8 q, key-chunk of 256 k); 4 tiles of 64 keys.
// Staging: K only, coalesced load->immediate LDS store (lesson R3: no
// long-liveness prefetch regs; lesson R5: distinct-row-per-lane reads must go
// through LDS — direct global K in the score phase is 64-way uncoalesced).
// Score: wave = 2 queries, lane = key; online softmax in registers.
// PV: lane = d, wave = key-quarter; V read DIRECT from global (lane-contiguous
// -> coalesced, L2-resident), P via wave-uniform broadcast b128. 2 barriers/tile.
#define TK 64
__global__ __launch_bounds__(256) void kD_part(const float* __restrict__ Q,
                                               const float* __restrict__ K,
                                               const float* __restrict__ V,
                                               const int* __restrict__ topk,
                                               float* __restrict__ pm,
                                               float* __restrict__ pl,
                                               float* __restrict__ pacc,
                                               int U, int nch) {
    int bi = blockIdx.x;
    int xcd = bi & 7, slot = bi >> 3;
    int per = nch * 8;
    int bh = xcd * 4 + slot / per;
    int rest = slot % per;
    int uc = rest >> 3, kc = rest & 7;

    int tid = threadIdx.x;
    int wv = tid >> 6, lane = tid & 63;

    __shared__ float Qs[8 * 64];
    __shared__ float Ks[TK * 68];              // pad 68: conflict-free b128 rows
    __shared__ float Ps[8 * 68];
    __shared__ float alph[8], mst[8], lst[8];
    __shared__ int   qidxs[8];
    float* accbuf = Ks;                        // epilogue alias (2048 <= 4352 f)

    if (tid < 8) {
        int gu = uc * 8 + tid;
        qidxs[tid] = (gu < U) ? topk[bh * U + gu] : 0;
    }
    __syncthreads();
#pragma unroll
    for (int step = 0; step < 2; ++step) {
        int uu = step * 4 + wv;
        int row = qidxs[uu];
        Qs[uu * 64 + lane] = Q[((long)bh * Lh + row) * Dh + lane] * 0.125f;
    }
    // Qs visibility covered by first post-stage barrier below.

    int kq = lane, ug = wv;
    float mrun0 = -INFINITY, mrun1 = -INFINITY;
    float lrun0 = 0.f, lrun1 = 0.f;
    float accv[8] = {0.f,0.f,0.f,0.f,0.f,0.f,0.f,0.f};

    const long kvbase = (long)bh * Lh * Dh;
    const float4* Kg4 = (const float4*)(K + kvbase);
    const float*  Vg  = V + kvbase;
    int kbase0 = kc * 256;

    for (int t = 0; t < 4; ++t) {
        int t0 = kbase0 + t * TK;
        // ---- stage K tile: coalesced load -> immediate store (short liveness) ----
        int f40 = t0 * (Dh / 4);
#pragma unroll
        for (int j = 0; j < 4; ++j) {
            int i = tid + 256 * j;             // 0..1023 float4s
            float4 kv = Kg4[f40 + i];
            int row = i >> 4, col = i & 15;
            *(float4*)(&Ks[row * 68 + col * 4]) = kv;
        }
        __syncthreads();                       // K tile visible; prev Ps reads done

        // ---- scores for u = 2ug, 2ug+1 at key kq ----
        float s0 = 0.f, s1 = 0.f;
#pragma unroll
        for (int j16 = 0; j16 < 16; ++j16) {
            float4 kf = *(const float4*)(&Ks[kq * 68 + j16 * 4]);
            float4 qa = *(const float4*)(&Qs[(2 * ug + 0) * 64 + j16 * 4]);
            float4 qb = *(const float4*)(&Qs[(2 * ug + 1) * 64 + j16 * 4]);
            s0 += kf.x * qa.x + kf.y * qa.y + kf.z * qa.z + kf.w * qa.w;
            s1 += kf.x * qb.x + kf.y * qb.y + kf.z * qb.z + kf.w * qb.w;
        }
        float m0 = s0, m1 = s1;
#pragma unroll
        for (int off = 1; off < 64; off <<= 1) {
            m0 = fmaxf(m0, __shfl_xor(m0, off));
            m1 = fmaxf(m1, __shfl_xor(m1, off));
        }
        float mn0 = fmaxf(mrun0, m0), mn1 = fmaxf(mrun1, m1);
        float a0 = __expf(mrun0 - mn0), a1 = __expf(mrun1 - mn1);
        float p0 = __expf(s0 - mn0),  p1 = __expf(s1 - mn1);
        float ls0 = p0, ls1 = p1;
#pragma unroll
        for (int off = 1; off < 64; off <<= 1) {
            ls0 += __shfl_xor(ls0, off);
            ls1 += __shfl_xor(ls1, off);
        }
        lrun0 = a0 * lrun0 + ls0;  lrun1 = a1 * lrun1 + ls1;
        mrun0 = mn0;               mrun1 = mn1;
        Ps[(2 * ug + 0) * 68 + kq] = p0;
        Ps[(2 * ug + 1) * 68 + kq] = p1;
        if (lane == 0) { alph[2 * ug] = a0; alph[2 * ug + 1] = a1; }
        __syncthreads();                       // Ps/alph visible; Ks reads done

        // ---- PV: lane=d, wave=key-quarter; V direct from global (coalesced) ----
        float vk[16];
        int vrow0 = t0 + wv * 16;
#pragma unroll
        for (int k = 0; k < 16; ++k)
            vk[k] = Vg[(long)(vrow0 + k) * Dh + lane];
#pragma unroll
        for (int u2 = 0; u2 < 8; ++u2) {
            const float* pb = &Ps[u2 * 68 + wv * 16];
            float4 pA = *(const float4*)(pb + 0);
            float4 pB = *(const float4*)(pb + 4);
            float4 pC = *(const float4*)(pb + 8);
            float4 pD = *(const float4*)(pb + 12);
            float av = alph[u2];
            float ac = accv[u2] * av;
            ac += pA.x*vk[0]  + pA.y*vk[1]  + pA.z*vk[2]  + pA.w*vk[3];
            ac += pB.x*vk[4]  + pB.y*vk[5]  + pB.z*vk[6]  + pB.w*vk[7];
            ac += pC.x*vk[8]  + pC.y*vk[9]  + pC.z*vk[10] + pC.w*vk[11];
            ac += pD.x*vk[12] + pD.y*vk[13] + pD.z*vk[14] + pD.w*vk[15];
            accv[u2] = ac;
        }
        // no barrier here: next stage's barrier orders Ps(t) reads vs Ps(t+1)
        // writes, and PV touches no Ks.
    }

    if (lane == 0) {
        mst[2 * ug] = mrun0;     lst[2 * ug] = lrun0;
        mst[2 * ug + 1] = mrun1; lst[2 * ug + 1] = lrun1;
    }
    // accbuf aliases Ks: safe — all Ks reads completed at last post-score barrier
#pragma unroll
    for (int u2 = 0; u2 < 8; ++u2)
        accbuf[wv * 512 + u2 * 64 + lane] = accv[u2];
    __syncthreads();

    int pbase = (bh * nch + uc) * 8;
    {
        int d = tid & 63, ua = tid >> 6;
#pragma unroll
        for (int h = 0; h < 2; ++h) {
            int u2 = ua + 4 * h;
            float o = accbuf[0 * 512 + u2 * 64 + d] + accbuf[1 * 512 + u2 * 64 + d]
                    + accbuf[2 * 512 + u2 * 64 + d] + accbuf[3 * 512 + u2 * 64 + d];
            pacc[((long)(pbase + u2) * 8 + kc) * 64 + d] = o;
        }
    }
    if (tid < 8) {
        int qp = (pbase + tid) * 8 + kc;
        pm[qp] = mst[tid];
        pl[qp] = lst[tid];
    }
}

// ---------------- Kernel F: combine split-K partials, scatter to ctx ----------------
__global__ __launch_bounds__(256) void kF_comb(const float* __restrict__ pm,
                                               const float* __restrict__ pl,
                                               const float* __restrict__ pacc,
                                               const int* __restrict__ topk,
                                               float* __restrict__ ctx,
                                               int U, int nch) {
    int bi = blockIdx.x;
    int bh = bi / nch, uc = bi % nch;
    int tid = threadIdx.x;
    int u = tid >> 5, t = tid & 31;
    int gu = uc * 8 + u;
    if (gu >= U) return;
    int qbase = (bh * nch + uc) * 8 + u;
    float m[8], l[8];
#pragma unroll
    for (int kc = 0; kc < 8; ++kc) { m[kc] = pm[qbase * 8 + kc]; l[kc] = pl[qbase * 8 + kc]; }
    float gm = m[0];
#pragma unroll
    for (int kc = 1; kc < 8; ++kc) gm = fmaxf(gm, m[kc]);
    float w[8]; float gl = 0.f;
#pragma unroll
    for (int kc = 0; kc < 8; ++kc) { w[kc] = __expf(m[kc] - gm); gl += l[kc] * w[kc]; }
    float inv = 1.0f / gl;
    float o0 = 0.f, o1 = 0.f;
#pragma unroll
    for (int kc = 0; kc < 8; ++kc) {
        const float* a = pacc + ((long)qbase * 8 + kc) * 64;
        o0 += a[t] * w[kc];
        o1 += a[t + 32] * w[kc];
    }
    int row = topk[bh * U + gu];
    float* crow = ctx + ((long)bh * Lh + row) * Dh;
    crow[t]      = o0 * inv;
    crow[t + 32] = o1 * inv;
}

extern "C" void kernel_launch(void* const* d_in, const int* in_sizes, int n_in,
                              void* d_out, int out_size, void* d_ws, size_t ws_size,
                              hipStream_t stream) {
    const float* Q    = (const float*)d_in[0];
    const float* K    = (const float*)d_in[1];
    const float* V    = (const float*)d_in[2];
    const int*   idxs = (const int*)d_in[3];
    float* ctx = (float*)d_out;

    int u = in_sizes[3] / Lh;    // 40
    int U = u;
    int nch = (U + 7) / 8;       // 5

    // workspace layout (floats)
    float*  wsf   = (float*)d_ws;
    float2* M2    = (float2*)wsf;                    // 131072 float2 = 262144 f
    int*    topk  = (int*)(wsf + 262144);            // 2048 ints
    float*  vpart = wsf + 262144 + 2048;             // 16384 f
    float*  pm    = wsf + 280576;                    // 32*nch*8*8
    float*  pl    = pm + 32 * nch * 8 * 8;
    float*  pacc  = pl + 32 * nch * 8 * 8;

    kAC    <<<2304,         256, 0, stream>>>(Q, K, V, idxs, M2, vpart, u);
    kBE    <<<4128,         256, 0, stream>>>(M2, vpart, topk, ctx, U);
    kD_part<<<BH * nch * 8, 256, 0, stream>>>(Q, K, V, topk, pm, pl, pacc, U, nch);
    kF_comb<<<BH * nch,     256, 0, stream>>>(pm, pl, pacc, topk, ctx, U, nch);
}